// Round 3
// baseline (241.011 us; speedup 1.0000x reference)
//
#include <hip/hip_runtime.h>
#include <hip/hip_bf16.h>
#include <stdint.h>

// Problem constants (fixed by reference): N=8192 tokens, D=1024, U=512, E=8, B=8 bases.
#define NTOK 8192
#define DDIM 1024
#define UDIM 512
#define NEXP 8

typedef __attribute__((ext_vector_type(8))) short bf16x8;
typedef __attribute__((ext_vector_type(4))) float f32x4;

// ---- helpers ---------------------------------------------------------------

__device__ __forceinline__ unsigned short f2bf(float f) {
  // round-to-nearest-even f32 -> bf16 (no NaN handling needed for this data)
  unsigned int u = __float_as_uint(f);
  u += 0x7FFFu + ((u >> 16) & 1u);
  return (unsigned short)(u >> 16);
}

__device__ __forceinline__ void gload16(const void* g, void* lds) {
  // async global->LDS, 16B per lane; LDS dest must be wave-uniform base (+lane*16 by HW)
  __builtin_amdgcn_global_load_lds(
      (__attribute__((address_space(1))) void*)(uintptr_t)g,
      (__attribute__((address_space(3))) void*)(uint32_t)(uintptr_t)lds,
      16, 0, 0);
}

// ---- prep: x -> bf16 -------------------------------------------------------

__global__ void k_cvt_x(const float* __restrict__ x, unsigned short* __restrict__ xb, int n) {
  const int stride = gridDim.x * blockDim.x;
  for (int i = blockIdx.x * blockDim.x + threadIdx.x; i * 4 < n; i += stride) {
    const float4 v = *(const float4*)(x + (size_t)i * 4);
    ushort4 o;
    o.x = f2bf(v.x); o.y = f2bf(v.y); o.z = f2bf(v.z); o.w = f2bf(v.w);
    *(ushort4*)(xb + (size_t)i * 4) = o;
  }
}

// ---- prep: transpose [E][R][C] f32 -> [E][C][R] bf16 -----------------------

__global__ void k_transpose(const float* __restrict__ src, unsigned short* __restrict__ dst,
                            int R, int C) {
  __shared__ float tile[32][33];
  const int e  = blockIdx.z;
  const int r0 = blockIdx.y << 5;
  const int c0 = blockIdx.x << 5;
  const int tc = threadIdx.x & 31;
  const int tr = threadIdx.x >> 5;  // 0..7
  const float* s = src + (size_t)e * R * C;
  unsigned short* d = dst + (size_t)e * R * C;
#pragma unroll
  for (int i = 0; i < 32; i += 8)
    tile[tr + i][tc] = s[(size_t)(r0 + tr + i) * C + c0 + tc];
  __syncthreads();
#pragma unroll
  for (int i = 0; i < 32; i += 8)
    d[(size_t)(c0 + tr + i) * R + r0 + tc] = f2bf(tile[tc][tr + i]);
}

// ---- gating: f32 logits + first-index argmax -------------------------------

__global__ void k_gate(const float* __restrict__ x, const float* __restrict__ Wg,
                       const float* __restrict__ bg, int* __restrict__ eidx,
                       int* __restrict__ counts) {
  const int lane = threadIdx.x & 63;
  const int n = (blockIdx.x << 2) + (threadIdx.x >> 6);  // 4 waves/block, 1 token/wave
  const float* xr = x + (size_t)n * DDIM;
  float acc[8] = {0.f, 0.f, 0.f, 0.f, 0.f, 0.f, 0.f, 0.f};
  for (int d = lane; d < DDIM; d += 64) {
    const float xv = xr[d];
    const float4 wa = *(const float4*)(Wg + d * 8);
    const float4 wb = *(const float4*)(Wg + d * 8 + 4);
    acc[0] = fmaf(xv, wa.x, acc[0]);
    acc[1] = fmaf(xv, wa.y, acc[1]);
    acc[2] = fmaf(xv, wa.z, acc[2]);
    acc[3] = fmaf(xv, wa.w, acc[3]);
    acc[4] = fmaf(xv, wb.x, acc[4]);
    acc[5] = fmaf(xv, wb.y, acc[5]);
    acc[6] = fmaf(xv, wb.z, acc[6]);
    acc[7] = fmaf(xv, wb.w, acc[7]);
  }
#pragma unroll
  for (int e = 0; e < 8; ++e) {
#pragma unroll
    for (int o = 32; o > 0; o >>= 1) acc[e] += __shfl_xor(acc[e], o, 64);
  }
  if (lane == 0) {
    int best = 0;
    float bv = acc[0] + bg[0];
#pragma unroll
    for (int e2 = 1; e2 < 8; ++e2) {
      const float v = acc[e2] + bg[e2];
      if (v > bv) { bv = v; best = e2; }  // strict > keeps first index on ties (np.argmax)
    }
    eidx[n] = best;
    atomicAdd(counts + best, 1);
  }
}

// ---- tiny scan + scatter ---------------------------------------------------

__global__ void k_scan(const int* __restrict__ counts, int* __restrict__ offsets,
                       int* __restrict__ cursors) {
  if (threadIdx.x == 0) {
    int run = 0;
    for (int e = 0; e < NEXP; ++e) { offsets[e] = run; cursors[e] = run; run += counts[e]; }
  }
}

__global__ void k_scatter(const int* __restrict__ eidx, int* __restrict__ cursors,
                          int* __restrict__ perm) {
  const int n = blockIdx.x * blockDim.x + threadIdx.x;
  const int e = eidx[n];
  const int pos = atomicAdd(cursors + e, 1);
  perm[pos] = n;  // order within expert nondeterministic; per-token output unaffected
}

// ---- fused expert kernel ---------------------------------------------------
// Block: 512 threads = 8 waves; tile = 64 tokens (one expert) x full U=512.
// Wave w owns output columns [w*64, w*64+64). 16x16x32 bf16 MFMA.
// LDS: A 4KB + B 32KB + H 64KB + ctrl 16KB + b1/scal 4KB + rows ~0.25KB = ~120KB.

struct __align__(16) ExpSmem {
  short Ab[64 * 32];      // A k-slice  [row][4 slots of 8 bf16], XOR-swizzled slots
  short Bb[512 * 32];     // B k-slice  [col][4 slots of 8 bf16], XOR-swizzled slots
  short Hs[64 * 512];     // H (swish out) bf16, byte ^= ((row&7)<<4) swizzle
  float ctrl_s[8 * 512];
  float b1_s[512];
  float scal_s[512];
  int rows_s[64];
};

__global__ __launch_bounds__(512) void k_expert(
    const unsigned short* __restrict__ xbf,   // [N][D] bf16
    const unsigned short* __restrict__ W1t,   // [E][U][D] bf16
    const unsigned short* __restrict__ projT, // [E][V][U] bf16
    const float* __restrict__ b1,             // [E][U]
    const float* __restrict__ ctrl,           // [E][8][U]
    const float* __restrict__ scaling,        // [E][U]
    const int* __restrict__ perm,
    const int* __restrict__ counts,
    const int* __restrict__ offsets,
    float* __restrict__ out)                  // [N][U] f32
{
  __shared__ ExpSmem sm;

  const int e    = blockIdx.x & 7;    // expert -> XCD (id%8) for L2 weight locality
  const int tile = blockIdx.x >> 3;
  const int cnt  = counts[e];
  if (tile * 64 >= cnt) return;
  const int off = offsets[e];
  const int m   = min(64, cnt - tile * 64);

  const int t    = threadIdx.x;
  const int w    = t >> 6;
  const int lane = t & 63;
  const int ln15 = lane & 15;
  const int g    = lane >> 4;            // k-group of this lane's fragment
  const int slot = g ^ (ln15 & 3);       // physical LDS slot after XOR swizzle

  // ---- stage per-expert params + row ids ----
#pragma unroll
  for (int j = 0; j < 8; ++j) sm.ctrl_s[t + j * 512] = ctrl[e * 8 * UDIM + t + j * 512];
  sm.b1_s[t]   = b1[e * UDIM + t];
  sm.scal_s[t] = scaling[e * UDIM + t];
  if (t < 64) {
    const int idx = tile * 64 + t;
    sm.rows_s[t] = perm[off + (idx < cnt ? idx : 0)];  // pad with a valid token
  }
  __syncthreads();

  const f32x4 zero4 = {0.f, 0.f, 0.f, 0.f};

  // ---- GEMM1: H = swish(X @ W1[e] + b1[e]),  K = 1024 ----
  f32x4 acc[4][4];
#pragma unroll
  for (int a = 0; a < 4; ++a)
#pragma unroll
    for (int b = 0; b < 4; ++b) acc[a][b] = zero4;

  for (int k0 = 0; k0 < DDIM; k0 += 32) {
    if (t < 256) {  // A tile: 64 rows x 32 k  (4KB)
      const int row = t >> 2, h = t & 3;
      gload16(xbf + (size_t)sm.rows_s[row] * DDIM + (k0 + ((h ^ (row & 3)) << 3)),
              (char*)sm.Ab + (t & ~63) * 16);
    }
#pragma unroll
    for (int j = 0; j < 4; ++j) {  // B tile: 512 cols x 32 k  (32KB)
      const int c = t + j * 512;
      const int u = c >> 2, h = c & 3;
      gload16(W1t + (((size_t)(e * UDIM + u)) << 10) + (k0 + ((h ^ (u & 3)) << 3)),
              (char*)sm.Bb + (c & ~63) * 16);
    }
    __syncthreads();
    bf16x8 af[4], bfr[4];
#pragma unroll
    for (int mt = 0; mt < 4; ++mt) {
      const int row = mt * 16 + ln15;
      af[mt] = *(const bf16x8*)((const char*)sm.Ab + row * 64 + slot * 16);
    }
#pragma unroll
    for (int nt = 0; nt < 4; ++nt) {
      const int u = w * 64 + nt * 16 + ln15;
      bfr[nt] = *(const bf16x8*)((const char*)sm.Bb + u * 64 + slot * 16);
    }
#pragma unroll
    for (int mt = 0; mt < 4; ++mt)
#pragma unroll
      for (int nt = 0; nt < 4; ++nt)
        acc[mt][nt] = __builtin_amdgcn_mfma_f32_16x16x32_bf16(af[mt], bfr[nt], acc[mt][nt], 0, 0, 0);
    __syncthreads();
  }

  // ---- epilogue1: +b1, swish, -> H (bf16, swizzled) ----
#pragma unroll
  for (int mt = 0; mt < 4; ++mt) {
#pragma unroll
    for (int nt = 0; nt < 4; ++nt) {
#pragma unroll
      for (int r = 0; r < 4; ++r) {
        const int row = mt * 16 + g * 4 + r;          // C layout: row=(lane>>4)*4+reg
        const int col = w * 64 + nt * 16 + ln15;      //           col=lane&15
        const float a  = acc[mt][nt][r] + sm.b1_s[col];
        const float hv = a / (1.f + __expf(-a));
        *(unsigned short*)((char*)sm.Hs + row * 1024 + ((col * 2) ^ ((row & 7) << 4))) = f2bf(hv);
      }
    }
  }
  __syncthreads();

  // ---- GEMM2: Z = H @ proj[e],  K = 512 ----
  f32x4 acc2[4][4];
#pragma unroll
  for (int a = 0; a < 4; ++a)
#pragma unroll
    for (int b = 0; b < 4; ++b) acc2[a][b] = zero4;

  for (int ks = 0; ks < UDIM; ks += 32) {
#pragma unroll
    for (int j = 0; j < 4; ++j) {  // B tile from projT
      const int c = t + j * 512;
      const int v = c >> 2, h = c & 3;
      gload16(projT + (((size_t)(e * UDIM + v)) << 9) + (ks + ((h ^ (v & 3)) << 3)),
              (char*)sm.Bb + (c & ~63) * 16);
    }
    __syncthreads();
    bf16x8 af2[4], bfr2[4];
#pragma unroll
    for (int mt = 0; mt < 4; ++mt) {
      const int row = mt * 16 + ln15;
      af2[mt] = *(const bf16x8*)((const char*)sm.Hs + row * 1024 +
                                 ((ks * 2 + g * 16) ^ ((row & 7) << 4)));
    }
#pragma unroll
    for (int nt = 0; nt < 4; ++nt) {
      const int v = w * 64 + nt * 16 + ln15;
      bfr2[nt] = *(const bf16x8*)((const char*)sm.Bb + v * 64 + slot * 16);
    }
#pragma unroll
    for (int mt = 0; mt < 4; ++mt)
#pragma unroll
      for (int nt = 0; nt < 4; ++nt)
        acc2[mt][nt] = __builtin_amdgcn_mfma_f32_16x16x32_bf16(af2[mt], bfr2[nt], acc2[mt][nt], 0, 0, 0);
    __syncthreads();
  }

  // ---- epilogue2: sigmoid -> RBF basis -> ctrl dot -> scale -> scatter store ----
  const float kInv7 = 0.14285714285714285f;  // knots = b/7
#pragma unroll
  for (int mt = 0; mt < 4; ++mt) {
#pragma unroll
    for (int nt = 0; nt < 4; ++nt) {
#pragma unroll
      for (int r = 0; r < 4; ++r) {
        const int row = mt * 16 + g * 4 + r;
        if (row < m) {
          const int col = w * 64 + nt * 16 + ln15;
          const float z  = acc2[mt][nt][r];
          const float xn = 1.f / (1.f + __expf(-z));
          float s = 0.f, dc = 0.f;
#pragma unroll
          for (int b = 0; b < 8; ++b) {
            const float d   = xn - (float)b * kInv7;
            const float bas = __expf(-32.f * d * d);   // exp(-dist/(2*(1/8)^2))
            s += bas;
            dc = fmaf(bas, sm.ctrl_s[b * 512 + col], dc);
          }
          out[(size_t)sm.rows_s[row] * UDIM + col] = dc / (s + 1e-6f) * sm.scal_s[col];
        }
      }
    }
  }
}

// ---- host launch -----------------------------------------------------------

extern "C" void kernel_launch(void* const* d_in, const int* in_sizes, int n_in,
                              void* d_out, int out_size, void* d_ws, size_t ws_size,
                              hipStream_t stream) {
  const float* x       = (const float*)d_in[0];
  const float* W1      = (const float*)d_in[1];
  const float* b1      = (const float*)d_in[2];
  const float* proj    = (const float*)d_in[3];
  const float* ctrl    = (const float*)d_in[4];
  const float* scaling = (const float*)d_in[5];
  const float* Wg      = (const float*)d_in[6];
  const float* bg      = (const float*)d_in[7];
  float* out = (float*)d_out;
  char* ws = (char*)d_ws;

  // workspace layout (~28.2 MB total)
  int* eidx    = (int*)(ws + 0);            // 32KB
  int* perm    = (int*)(ws + 32768);        // 32KB
  int* counts  = (int*)(ws + 65536);        // 32B
  int* offsets = (int*)(ws + 65536 + 32);   // 32B
  int* cursors = (int*)(ws + 65536 + 64);   // 32B
  unsigned short* xbf   = (unsigned short*)(ws + 131072);                        // 16MB
  unsigned short* W1t   = (unsigned short*)(ws + 131072 + 16777216);             // 8MB
  unsigned short* projT = (unsigned short*)(ws + 131072 + 16777216 + 8388608);   // 4MB

  hipMemsetAsync(ws + 65536, 0, 128, stream);

  k_cvt_x<<<4096, 256, 0, stream>>>(x, xbf, NTOK * DDIM);
  k_transpose<<<dim3(UDIM / 32, DDIM / 32, NEXP), 256, 0, stream>>>(W1, W1t, DDIM, UDIM);
  k_transpose<<<dim3(UDIM / 32, UDIM / 32, NEXP), 256, 0, stream>>>(proj, projT, UDIM, UDIM);
  k_gate<<<NTOK / 4, 256, 0, stream>>>(x, Wg, bg, eidx, counts);
  k_scan<<<1, 64, 0, stream>>>(counts, offsets, cursors);
  k_scatter<<<NTOK / 256, 256, 0, stream>>>(eidx, cursors, perm);
  k_expert<<<NEXP * (NTOK / 64), 512, 0, stream>>>(xbf, W1t, projT, b1, ctrl, scaling,
                                                   perm, counts, offsets, out);
}